// Round 3
// baseline (359.352 us; speedup 1.0000x reference)
//
#include <hip/hip_runtime.h>
#include <hip/hip_bf16.h>

#define K_DIM 4096
#define N_DIM 12288
#define B_DIM 64
#define G_DIM 64          // K / 64 groups
#define R_DIM 32
#define AS_LD 68          // padded leading dim for s_as[g][b]

typedef int v4i __attribute__((ext_vector_type(4)));

// ---------------------------------------------------------------------------
// Kernel 1: smoothing divide + per-(token,group) int4 symmetric quantization.
// Grid = B*G/4 = 1024 blocks; 4 waves/block, one wave per group, one lane per k.
// ---------------------------------------------------------------------------
__global__ __launch_bounds__(256) void quant_kernel(
    const float* __restrict__ x, const float* __restrict__ smooth,
    char* __restrict__ xq, float* __restrict__ ascale) {
    const int b = blockIdx.x >> 4;
    const int gq = blockIdx.x & 15;
    const int w = threadIdx.x >> 6, lane = threadIdx.x & 63;
    const int g = gq * 4 + w;
    const int k = g * 64 + lane;
    const float xd = x[b * K_DIM + k] / smooth[k];
    float a = fabsf(xd);
    #pragma unroll
    for (int off = 32; off; off >>= 1) a = fmaxf(a, __shfl_xor(a, off));
    const float as = fmaxf(a / 7.0f, 1e-8f);
    float q = rintf(xd / as);
    q = fminf(fmaxf(q, -8.0f), 7.0f);
    xq[b * K_DIM + k] = (char)(int)q;
    if (lane == 0) ascale[b * G_DIM + g] = as;
}

// ---------------------------------------------------------------------------
// Kernel 2: t[b, r] += partial lora-down dot. Grid = 64 x 16 k-chunks.
// ---------------------------------------------------------------------------
__global__ __launch_bounds__(256) void lora_down_kernel(
    const float* __restrict__ x, const float* __restrict__ smooth,
    const float* __restrict__ ld, float* __restrict__ t) {
    const int b = blockIdx.x >> 4;
    const int kc = blockIdx.x & 15;
    const int r = threadIdx.x & 31;
    const int c = threadIdx.x >> 5;   // 0..7
    const int k0 = kc * 256 + c * 32;
    float acc = 0.f;
    #pragma unroll 8
    for (int k = k0; k < k0 + 32; ++k) {
        const float xd = x[b * K_DIM + k] / smooth[k];
        acc += xd * ld[k * R_DIM + r];
    }
    __shared__ float red[256];
    red[threadIdx.x] = acc;
    __syncthreads();
    if (threadIdx.x < 32) {
        float s = 0.f;
        #pragma unroll
        for (int c2 = 0; c2 < 8; ++c2) s += red[c2 * 32 + threadIdx.x];
        atomicAdd(&t[b * R_DIM + threadIdx.x], s);
    }
}

// ---------------------------------------------------------------------------
// Kernel 3: main W4A4 GEMM via mfma_i32_16x16x64_i8.
// Grid: 768 n-tiles x 2 K-halves = 1536 blocks (6/CU queued, 4 resident at
// __launch_bounds__(256,4) -> 16 waves/CU). Wave w covers 8 groups of its
// K-half, FULLY UNROLLED straight-line so the scheduler hoists the
// independent q_w/xq loads as deep as the 128-VGPR budget allows (no
// loop-carried rotation -> no per-iteration vmcnt(0)).
// Both K-halves atomicAdd into zeroed out; ks==0 also adds bias + lora.
// ---------------------------------------------------------------------------
__global__ __launch_bounds__(256, 4) void main_kernel(
    const int* __restrict__ qw, const float* __restrict__ wscales,
    const char* __restrict__ xq, const float* __restrict__ ascale,
    const float* __restrict__ t, const float* __restrict__ lora_up,
    const float* __restrict__ bias, float* __restrict__ out) {
    __shared__ float smem[4096];              // 16 KB, two aliased phases
    float* s_ws = smem;                       // [32][16]  phase 1
    float* s_as = smem + 512;                 // [32][AS_LD] phase 1
    float* s_red = smem;                      // [4096]    phase 2 (after sync)

    const int nt = blockIdx.x >> 1;
    const int ks = blockIdx.x & 1;            // K-half
    const int n0 = nt * 16;
    const int tid = threadIdx.x;

    for (int i = tid; i < 32 * 16; i += 256) {
        const int g = i >> 4, j = i & 15;
        s_ws[i] = wscales[(ks * 32 + g) * N_DIM + n0 + j];
    }
    for (int i = tid; i < B_DIM * 32; i += 256) {
        const int b = i >> 5, gg = i & 31;
        s_as[gg * AS_LD + b] = ascale[b * G_DIM + ks * 32 + gg];
    }
    __syncthreads();

    const int w = tid >> 6, lane = tid & 63;
    const int col = lane & 15, quad = lane >> 4;
    const int gl0 = w * 8;                    // local group base (0..31)

    float facc[4][4];
    #pragma unroll
    for (int bt = 0; bt < 4; ++bt)
        #pragma unroll
        for (int r = 0; r < 4; ++r) facc[bt][r] = 0.f;

    const v4i zero = {0, 0, 0, 0};
    const size_t kstart = (size_t)(ks * 32 + gl0) * 64 + quad * 16;
    const int* qbase = qw + (size_t)(n0 + col) * K_DIM + kstart;
    const char* xbase = xq + (size_t)col * K_DIM + kstart;

    #pragma unroll
    for (int gi = 0; gi < 8; ++gi) {
        const int* p = qbase + gi * 64;
        const v4i q0 = *(const v4i*)(p);
        const v4i q1 = *(const v4i*)(p + 4);
        const v4i q2 = *(const v4i*)(p + 8);
        const v4i q3 = *(const v4i*)(p + 12);
        v4i bfrag;
        bfrag.x = (q0.x & 255) | ((q0.y & 255) << 8) | ((q0.z & 255) << 16) | (q0.w << 24);
        bfrag.y = (q1.x & 255) | ((q1.y & 255) << 8) | ((q1.z & 255) << 16) | (q1.w << 24);
        bfrag.z = (q2.x & 255) | ((q2.y & 255) << 8) | ((q2.z & 255) << 16) | (q2.w << 24);
        bfrag.w = (q3.x & 255) | ((q3.y & 255) << 8) | ((q3.z & 255) << 16) | (q3.w << 24);
        const int gl = gl0 + gi;
        const float wsc = s_ws[gl * 16 + col];
        #pragma unroll
        for (int bt = 0; bt < 4; ++bt) {
            const v4i xa = *(const v4i*)(xbase + (size_t)(bt * 16) * K_DIM + gi * 64);
            const v4i d = __builtin_amdgcn_mfma_i32_16x16x64_i8(xa, bfrag, zero, 0, 0, 0);
            const float4 as4 = *(const float4*)&s_as[gl * AS_LD + bt * 16 + quad * 4];
            facc[bt][0] = fmaf(as4.x * wsc, (float)d[0], facc[bt][0]);
            facc[bt][1] = fmaf(as4.y * wsc, (float)d[1], facc[bt][1]);
            facc[bt][2] = fmaf(as4.z * wsc, (float)d[2], facc[bt][2]);
            facc[bt][3] = fmaf(as4.w * wsc, (float)d[3], facc[bt][3]);
        }
    }

    __syncthreads();   // all waves done reading s_ws/s_as (aliased by s_red)
    #pragma unroll
    for (int bt = 0; bt < 4; ++bt)
        #pragma unroll
        for (int r = 0; r < 4; ++r)
            s_red[w * 1024 + lane * 16 + bt * 4 + r] = facc[bt][r];
    __syncthreads();

    #pragma unroll
    for (int i = 0; i < 4; ++i) {
        const int o = tid + i * 256;          // 0..1023
        float acc = s_red[o] + s_red[1024 + o] + s_red[2048 + o] + s_red[3072 + o];
        const int lane_o = o >> 4;
        const int bt = (o >> 2) & 3, r = o & 3;
        const int b = bt * 16 + (lane_o >> 4) * 4 + r;
        const int n = n0 + (lane_o & 15);
        if (ks == 0) {
            float e = bias[n];
            const float4* tp = (const float4*)(t + b * R_DIM);
            const float4* lp = (const float4*)(lora_up + (size_t)n * R_DIM);
            #pragma unroll
            for (int r2 = 0; r2 < R_DIM / 4; ++r2) {
                const float4 tv = tp[r2], lv = lp[r2];
                e += tv.x * lv.x + tv.y * lv.y + tv.z * lv.z + tv.w * lv.w;
            }
            acc += e;
        }
        atomicAdd(&out[(size_t)b * N_DIM + n], acc);
    }
}

// ---------------------------------------------------------------------------
extern "C" void kernel_launch(void* const* d_in, const int* in_sizes, int n_in,
                              void* d_out, int out_size, void* d_ws, size_t ws_size,
                              hipStream_t stream) {
    const float* x         = (const float*)d_in[0];
    const int*   q_w       = (const int*)d_in[1];
    const float* wscales   = (const float*)d_in[2];
    const float* lora_down = (const float*)d_in[3];
    const float* lora_up   = (const float*)d_in[4];
    const float* smooth    = (const float*)d_in[5];
    const float* bias      = (const float*)d_in[6];
    float* out = (float*)d_out;

    char*  xq     = (char*)d_ws;                            // 256 KB
    float* ascale = (float*)((char*)d_ws + 262144);         // 16 KB
    float* t      = (float*)((char*)d_ws + 262144 + 16384); // 8 KB

    hipMemsetAsync(t, 0, B_DIM * R_DIM * sizeof(float), stream);
    hipMemsetAsync(out, 0, (size_t)B_DIM * N_DIM * sizeof(float), stream);
    quant_kernel<<<B_DIM * 16, 256, 0, stream>>>(x, smooth, xq, ascale);
    lora_down_kernel<<<B_DIM * 16, 256, 0, stream>>>(x, smooth, lora_down, t);
    main_kernel<<<N_DIM / 16 * 2, 256, 0, stream>>>(q_w, wscales, xq, ascale,
                                                    t, lora_up, bias, out);
}

// Round 4
// 346.715 us; speedup vs baseline: 1.0364x; 1.0364x over previous
//
#include <hip/hip_runtime.h>
#include <hip/hip_bf16.h>

#define K_DIM 4096
#define N_DIM 12288
#define B_DIM 64
#define G_DIM 64          // K / 64 groups
#define R_DIM 32
#define AS_LD 68          // padded leading dim for s_as[g][b]
#define NT_DIM 768        // N / 16 n-tiles

typedef int v4i __attribute__((ext_vector_type(4)));

__device__ __forceinline__ int pack4(const v4i a) {
    return (a.x & 255) | ((a.y & 255) << 8) | ((a.z & 255) << 16) | (a.w << 24);
}

// ---------------------------------------------------------------------------
// Kernel 1 (packed path): quantize + write xq in MFMA-lane-packed layout:
//   xq_p[bt][g][quad*16 + (b&15)][16B], byte (k&15).
// Grid = B*16 blocks, 4 waves each = one (b, g) per wave, one k per lane.
// ---------------------------------------------------------------------------
__global__ __launch_bounds__(256) void quant_packed_kernel(
    const float* __restrict__ x, const float* __restrict__ smooth,
    char* __restrict__ xq_p, float* __restrict__ ascale) {
    const int b = blockIdx.x >> 4;
    const int gq = blockIdx.x & 15;
    const int w = threadIdx.x >> 6, lane = threadIdx.x & 63;
    const int g = gq * 4 + w;
    const int k = g * 64 + lane;
    const float xd = x[b * K_DIM + k] / smooth[k];
    float a = fabsf(xd);
    #pragma unroll
    for (int off = 32; off; off >>= 1) a = fmaxf(a, __shfl_xor(a, off));
    const float as = fmaxf(a / 7.0f, 1e-8f);
    float q = rintf(xd / as);
    q = fminf(fmaxf(q, -8.0f), 7.0f);
    const int bt = b >> 4, b15 = b & 15;
    const int quad = lane >> 4, kin = lane & 15;
    xq_p[((((size_t)bt * G_DIM + g) * 64) + quad * 16 + b15) * 16 + kin] = (char)(int)q;
    if (lane == 0) ascale[b * G_DIM + g] = as;
}

// ---------------------------------------------------------------------------
// Kernel 1b (fallback): flat xq layout (R2 version).
// ---------------------------------------------------------------------------
__global__ __launch_bounds__(256) void quant_flat_kernel(
    const float* __restrict__ x, const float* __restrict__ smooth,
    char* __restrict__ xq, float* __restrict__ ascale) {
    const int b = blockIdx.x >> 4;
    const int gq = blockIdx.x & 15;
    const int w = threadIdx.x >> 6, lane = threadIdx.x & 63;
    const int g = gq * 4 + w;
    const int k = g * 64 + lane;
    const float xd = x[b * K_DIM + k] / smooth[k];
    float a = fabsf(xd);
    #pragma unroll
    for (int off = 32; off; off >>= 1) a = fmaxf(a, __shfl_xor(a, off));
    const float as = fmaxf(a / 7.0f, 1e-8f);
    float q = rintf(xd / as);
    q = fminf(fmaxf(q, -8.0f), 7.0f);
    xq[b * K_DIM + k] = (char)(int)q;
    if (lane == 0) ascale[b * G_DIM + g] = as;
}

// ---------------------------------------------------------------------------
// Kernel 2: t[b, r] += partial lora-down dot. Grid = 64 x 16 k-chunks.
// ---------------------------------------------------------------------------
__global__ __launch_bounds__(256) void lora_down_kernel(
    const float* __restrict__ x, const float* __restrict__ smooth,
    const float* __restrict__ ld, float* __restrict__ t) {
    const int b = blockIdx.x >> 4;
    const int kc = blockIdx.x & 15;
    const int r = threadIdx.x & 31;
    const int c = threadIdx.x >> 5;   // 0..7
    const int k0 = kc * 256 + c * 32;
    float acc = 0.f;
    #pragma unroll 8
    for (int k = k0; k < k0 + 32; ++k) {
        const float xd = x[b * K_DIM + k] / smooth[k];
        acc += xd * ld[k * R_DIM + r];
    }
    __shared__ float red[256];
    red[threadIdx.x] = acc;
    __syncthreads();
    if (threadIdx.x < 32) {
        float s = 0.f;
        #pragma unroll
        for (int c2 = 0; c2 < 8; ++c2) s += red[c2 * 32 + threadIdx.x];
        atomicAdd(&t[b * R_DIM + threadIdx.x], s);
    }
}

// ---------------------------------------------------------------------------
// Kernel 3: prepack q_w (int32, row-major) -> q8 MFMA-lane-packed:
//   q8[nt][g][lane][16B] where lane=(quad*16+col) holds
//   q_w[nt*16+col][g*64+quad*16 .. +16) packed to bytes.
// Each thread handles one entry: reads 4x dwordx4 (256 B contiguous from ONE
// row -> no line duplication), writes one dwordx4 with consecutive lanes ->
// consecutive addresses (perfectly coalesced 1 KB/instr). 4 entries/thread
// unrolled = 16 independent loads in flight.
// Grid = 768*64*64 entries / 1024 per block = 3072 blocks.
// ---------------------------------------------------------------------------
__global__ __launch_bounds__(256) void prepack_kernel(
    const int* __restrict__ qw, v4i* __restrict__ q8) {
    const int tid = threadIdx.x;
    const size_t ebase = (size_t)blockIdx.x * 1024;
    #pragma unroll
    for (int p = 0; p < 4; ++p) {
        const size_t e = ebase + p * 256 + tid;
        const int ntg = (int)(e >> 6);          // nt*64 + g
        const int l = (int)e & 63;
        const int nt = ntg >> 6, g = ntg & 63;
        const int row = nt * 16 + (l & 15);
        const int k0 = g * 64 + (l >> 4) * 16;
        const int* s = qw + (size_t)row * K_DIM + k0;
        const v4i a0 = *(const v4i*)(s);
        const v4i a1 = *(const v4i*)(s + 4);
        const v4i a2 = *(const v4i*)(s + 8);
        const v4i a3 = *(const v4i*)(s + 12);
        v4i o;
        o.x = pack4(a0); o.y = pack4(a1); o.z = pack4(a2); o.w = pack4(a3);
        q8[e] = o;
    }
}

// ---------------------------------------------------------------------------
// Kernel 4: main W4A4 GEMM, packed inputs. Grid = 768 n-tile blocks.
// Wave w covers groups [16w, 16w+16), fully unrolled. Per group: ONE
// coalesced dwordx4 of q8 (1 KB/wave-instr) + 4 coalesced xa loads + 4 MFMA.
// No int packing in the hot loop. s_red reduce + direct store epilogue.
// ---------------------------------------------------------------------------
__global__ __launch_bounds__(256) void main_packed_kernel(
    const v4i* __restrict__ q8, const float* __restrict__ wscales,
    const v4i* __restrict__ xq_p, const float* __restrict__ ascale,
    const float* __restrict__ t, const float* __restrict__ lora_up,
    const float* __restrict__ bias, float* __restrict__ out) {
    __shared__ float smem[5440];              // 21.8 KB, two aliased phases
    float* s_ws = smem;                       // [64][16]   phase 1
    float* s_as = smem + 1024;                // [64][AS_LD] phase 1
    float* s_red = smem;                      // [4096]     phase 2

    const int nt = blockIdx.x;
    const int n0 = nt * 16;
    const int tid = threadIdx.x;

    for (int i = tid; i < G_DIM * 16; i += 256) {
        const int g = i >> 4, j = i & 15;
        s_ws[i] = wscales[g * N_DIM + n0 + j];
    }
    for (int i = tid; i < B_DIM * G_DIM; i += 256) {
        const int b = i >> 6, g = i & 63;
        s_as[g * AS_LD + b] = ascale[i];
    }
    __syncthreads();

    const int w = tid >> 6, lane = tid & 63;
    const int col = lane & 15, quad = lane >> 4;
    const int g0 = w * 16;

    float facc[4][4];
    #pragma unroll
    for (int bt = 0; bt < 4; ++bt)
        #pragma unroll
        for (int r = 0; r < 4; ++r) facc[bt][r] = 0.f;

    const v4i zero = {0, 0, 0, 0};
    const v4i* qptr = q8 + ((size_t)nt * G_DIM + g0) * 64 + lane;
    const v4i* xptr = xq_p + (size_t)g0 * 64 + lane;

    #pragma unroll
    for (int gi = 0; gi < 16; ++gi) {
        const int g = g0 + gi;
        const v4i bq = qptr[gi * 64];
        const float wsc = s_ws[g * 16 + col];
        #pragma unroll
        for (int bt = 0; bt < 4; ++bt) {
            const v4i xa = xptr[((size_t)bt * G_DIM + gi) * 64];
            const v4i d = __builtin_amdgcn_mfma_i32_16x16x64_i8(xa, bq, zero, 0, 0, 0);
            const float4 as4 = *(const float4*)&s_as[g * AS_LD + bt * 16 + quad * 4];
            facc[bt][0] = fmaf(as4.x * wsc, (float)d[0], facc[bt][0]);
            facc[bt][1] = fmaf(as4.y * wsc, (float)d[1], facc[bt][1]);
            facc[bt][2] = fmaf(as4.z * wsc, (float)d[2], facc[bt][2]);
            facc[bt][3] = fmaf(as4.w * wsc, (float)d[3], facc[bt][3]);
        }
    }

    __syncthreads();   // all waves done with s_ws/s_as (aliased by s_red)
    #pragma unroll
    for (int bt = 0; bt < 4; ++bt)
        #pragma unroll
        for (int r = 0; r < 4; ++r)
            s_red[w * 1024 + lane * 16 + bt * 4 + r] = facc[bt][r];
    __syncthreads();

    #pragma unroll
    for (int i = 0; i < 4; ++i) {
        const int o = tid + i * 256;          // 0..1023
        float acc = s_red[o] + s_red[1024 + o] + s_red[2048 + o] + s_red[3072 + o];
        const int lane_o = o >> 4;
        const int bt = (o >> 2) & 3, r = o & 3;
        const int b = bt * 16 + (lane_o >> 4) * 4 + r;
        const int n = n0 + (lane_o & 15);
        acc += bias[n];
        const float4* tp = (const float4*)(t + b * R_DIM);
        const float4* lp = (const float4*)(lora_up + (size_t)n * R_DIM);
        #pragma unroll
        for (int r2 = 0; r2 < R_DIM / 4; ++r2) {
            const float4 tv = tp[r2], lv = lp[r2];
            acc += tv.x * lv.x + tv.y * lv.y + tv.z * lv.z + tv.w * lv.w;
        }
        out[(size_t)b * N_DIM + n] = acc;
    }
}

// ---------------------------------------------------------------------------
// Fallback main (R2 structure, reads raw q_w): used only if ws_size < 51 MB.
// ---------------------------------------------------------------------------
__global__ __launch_bounds__(256) void main_direct_kernel(
    const int* __restrict__ qw, const float* __restrict__ wscales,
    const char* __restrict__ xq, const float* __restrict__ ascale,
    const float* __restrict__ t, const float* __restrict__ lora_up,
    const float* __restrict__ bias, float* __restrict__ out) {
    __shared__ float smem[5440];
    float* s_ws = smem;
    float* s_as = smem + 1024;
    float* s_red = smem;

    const int nt = blockIdx.x;
    const int n0 = nt * 16;
    const int tid = threadIdx.x;

    for (int i = tid; i < G_DIM * 16; i += 256) {
        const int g = i >> 4, j = i & 15;
        s_ws[i] = wscales[g * N_DIM + n0 + j];
    }
    for (int i = tid; i < B_DIM * G_DIM; i += 256) {
        const int b = i >> 6, g = i & 63;
        s_as[g * AS_LD + b] = ascale[i];
    }
    __syncthreads();

    const int w = tid >> 6, lane = tid & 63;
    const int col = lane & 15, quad = lane >> 4;
    const int g0 = w * 16;

    float facc[4][4];
    #pragma unroll
    for (int bt = 0; bt < 4; ++bt)
        #pragma unroll
        for (int r = 0; r < 4; ++r) facc[bt][r] = 0.f;

    const v4i zero = {0, 0, 0, 0};
    const int* qbase = qw + (size_t)(n0 + col) * K_DIM + (size_t)g0 * 64 + quad * 16;
    const char* xbase = xq + (size_t)col * K_DIM + (size_t)g0 * 64 + quad * 16;

    #pragma unroll
    for (int gi = 0; gi < 16; ++gi) {
        const int* p = qbase + gi * 64;
        const v4i q0 = *(const v4i*)(p);
        const v4i q1 = *(const v4i*)(p + 4);
        const v4i q2 = *(const v4i*)(p + 8);
        const v4i q3 = *(const v4i*)(p + 12);
        v4i bfrag;
        bfrag.x = pack4(q0); bfrag.y = pack4(q1);
        bfrag.z = pack4(q2); bfrag.w = pack4(q3);
        const int g = g0 + gi;
        const float wsc = s_ws[g * 16 + col];
        #pragma unroll
        for (int bt = 0; bt < 4; ++bt) {
            const v4i xa = *(const v4i*)(xbase + (size_t)(bt * 16) * K_DIM + gi * 64);
            const v4i d = __builtin_amdgcn_mfma_i32_16x16x64_i8(xa, bfrag, zero, 0, 0, 0);
            const float4 as4 = *(const float4*)&s_as[g * AS_LD + bt * 16 + quad * 4];
            facc[bt][0] = fmaf(as4.x * wsc, (float)d[0], facc[bt][0]);
            facc[bt][1] = fmaf(as4.y * wsc, (float)d[1], facc[bt][1]);
            facc[bt][2] = fmaf(as4.z * wsc, (float)d[2], facc[bt][2]);
            facc[bt][3] = fmaf(as4.w * wsc, (float)d[3], facc[bt][3]);
        }
    }

    __syncthreads();
    #pragma unroll
    for (int bt = 0; bt < 4; ++bt)
        #pragma unroll
        for (int r = 0; r < 4; ++r)
            s_red[w * 1024 + lane * 16 + bt * 4 + r] = facc[bt][r];
    __syncthreads();

    #pragma unroll
    for (int i = 0; i < 4; ++i) {
        const int o = tid + i * 256;
        float acc = s_red[o] + s_red[1024 + o] + s_red[2048 + o] + s_red[3072 + o];
        const int lane_o = o >> 4;
        const int bt = (o >> 2) & 3, r = o & 3;
        const int b = bt * 16 + (lane_o >> 4) * 4 + r;
        const int n = n0 + (lane_o & 15);
        acc += bias[n];
        const float4* tp = (const float4*)(t + b * R_DIM);
        const float4* lp = (const float4*)(lora_up + (size_t)n * R_DIM);
        #pragma unroll
        for (int r2 = 0; r2 < R_DIM / 4; ++r2) {
            const float4 tv = tp[r2], lv = lp[r2];
            acc += tv.x * lv.x + tv.y * lv.y + tv.z * lv.z + tv.w * lv.w;
        }
        out[(size_t)b * N_DIM + n] = acc;
    }
}

// ---------------------------------------------------------------------------
extern "C" void kernel_launch(void* const* d_in, const int* in_sizes, int n_in,
                              void* d_out, int out_size, void* d_ws, size_t ws_size,
                              hipStream_t stream) {
    const float* x         = (const float*)d_in[0];
    const int*   q_w       = (const int*)d_in[1];
    const float* wscales   = (const float*)d_in[2];
    const float* lora_down = (const float*)d_in[3];
    const float* lora_up   = (const float*)d_in[4];
    const float* smooth    = (const float*)d_in[5];
    const float* bias      = (const float*)d_in[6];
    float* out = (float*)d_out;

    char*  xq     = (char*)d_ws;                            // 256 KB (either layout)
    float* ascale = (float*)((char*)d_ws + 262144);         // 16 KB
    float* t      = (float*)((char*)d_ws + 262144 + 16384); // 8 KB
    v4i*   q8     = (v4i*)((char*)d_ws + 524288);           // 48 MB packed weights

    const size_t need = 524288 + (size_t)NT_DIM * G_DIM * 64 * 16;

    hipMemsetAsync(t, 0, B_DIM * R_DIM * sizeof(float), stream);
    lora_down_kernel<<<B_DIM * 16, 256, 0, stream>>>(x, smooth, lora_down, t);

    if (ws_size >= need) {
        quant_packed_kernel<<<B_DIM * 16, 256, 0, stream>>>(x, smooth, xq, ascale);
        prepack_kernel<<<3072, 256, 0, stream>>>(q_w, q8);
        main_packed_kernel<<<NT_DIM, 256, 0, stream>>>(q8, wscales, (const v4i*)xq,
                                                       ascale, t, lora_up, bias, out);
    } else {
        quant_flat_kernel<<<B_DIM * 16, 256, 0, stream>>>(x, smooth, xq, ascale);
        main_direct_kernel<<<NT_DIM, 256, 0, stream>>>(q_w, wscales, xq, ascale,
                                                       t, lora_up, bias, out);
    }
}

// Round 5
// 299.681 us; speedup vs baseline: 1.1991x; 1.1569x over previous
//
#include <hip/hip_runtime.h>
#include <hip/hip_bf16.h>

#define K_DIM 4096
#define N_DIM 12288
#define B_DIM 64
#define G_DIM 64          // K / 64 groups
#define R_DIM 32
#define NT_DIM 768        // N / 16 n-tiles

typedef int v4i __attribute__((ext_vector_type(4)));

__device__ __forceinline__ int pack4(const v4i a) {
    return (a.x & 255) | ((a.y & 255) << 8) | ((a.z & 255) << 16) | (a.w << 24);
}

// ---------------------------------------------------------------------------
// Kernel 1: quantize + write xq in MFMA-lane-packed layout:
//   xq_p[bt][g][quad*16 + (b&15)][16B], byte (k&15).
// Grid = B*16 blocks, 4 waves each = one (b, g) per wave, one k per lane.
// rintf == jnp.round (half-to-even); IEEE div matches reference.
// ---------------------------------------------------------------------------
__global__ __launch_bounds__(256) void quant_packed_kernel(
    const float* __restrict__ x, const float* __restrict__ smooth,
    char* __restrict__ xq_p, float* __restrict__ ascale) {
    const int b = blockIdx.x >> 4;
    const int gq = blockIdx.x & 15;
    const int w = threadIdx.x >> 6, lane = threadIdx.x & 63;
    const int g = gq * 4 + w;
    const int k = g * 64 + lane;
    const float xd = x[b * K_DIM + k] / smooth[k];
    float a = fabsf(xd);
    #pragma unroll
    for (int off = 32; off; off >>= 1) a = fmaxf(a, __shfl_xor(a, off));
    const float as = fmaxf(a / 7.0f, 1e-8f);
    float q = rintf(xd / as);
    q = fminf(fmaxf(q, -8.0f), 7.0f);
    const int bt = b >> 4, b15 = b & 15;
    const int quad = lane >> 4, kin = lane & 15;
    xq_p[((((size_t)bt * G_DIM + g) * 64) + quad * 16 + b15) * 16 + kin] = (char)(int)q;
    if (lane == 0) ascale[b * G_DIM + g] = as;
}

// ---------------------------------------------------------------------------
// Kernel 2: t[b, r] += partial lora-down dot. Grid = 64 x 16 k-chunks.
// ---------------------------------------------------------------------------
__global__ __launch_bounds__(256) void lora_down_kernel(
    const float* __restrict__ x, const float* __restrict__ smooth,
    const float* __restrict__ ld, float* __restrict__ t) {
    const int b = blockIdx.x >> 4;
    const int kc = blockIdx.x & 15;
    const int r = threadIdx.x & 31;
    const int c = threadIdx.x >> 5;   // 0..7
    const int k0 = kc * 256 + c * 32;
    float acc = 0.f;
    #pragma unroll 8
    for (int k = k0; k < k0 + 32; ++k) {
        const float xd = x[b * K_DIM + k] / smooth[k];
        acc += xd * ld[k * R_DIM + r];
    }
    __shared__ float red[256];
    red[threadIdx.x] = acc;
    __syncthreads();
    if (threadIdx.x < 32) {
        float s = 0.f;
        #pragma unroll
        for (int c2 = 0; c2 < 8; ++c2) s += red[c2 * 32 + threadIdx.x];
        atomicAdd(&t[b * R_DIM + threadIdx.x], s);
    }
}

// ---------------------------------------------------------------------------
// Kernel 3: fused main. Grid = 768 blocks (one 16-col n-tile each), 4 waves.
// Wave w owns b-tile w (tokens 16w..16w+15) -> no cross-wave reduction.
// K-loop: 16 chunks of 4 groups. Per chunk:
//   staging (all 256 threads): thread t reads q_w row n0+(t>>4), int32 cols
//   (t&15)*4 + i*64 (per instr: 4x 256 B contiguous segments, every byte
//   used), packs 4xint32 -> int8x4, writes to LDS chunk buf (row stride
//   272 B -> uniform bank coverage). Double-buffered: loads for chunk j+1
//   issue before compute(j); pack/write after (vmcnt covered by 4 MFMA +
//   LDS + xa-load latency of compute).
//   compute (per wave): 4x { ds_read_b128 bq, coalesced 1KB xa load (L2),
//   mfma_i32_16x16x64_i8, scale-FMA }.
// Epilogue: bias + rank-32 lora dot (lora_up row cached in regs, t in LDS),
// direct coalesced stores.
// ---------------------------------------------------------------------------
__global__ __launch_bounds__(256) void main_fused_kernel(
    const int* __restrict__ qw, const float* __restrict__ wscales,
    const v4i* __restrict__ xq_p, const float* __restrict__ ascale,
    const float* __restrict__ t, const float* __restrict__ lora_up,
    const float* __restrict__ bias, float* __restrict__ out) {
    __shared__ float s_ws[G_DIM * 16];      // [g][j]   4 KB
    __shared__ float s_as[G_DIM * 68];      // [g][b]  17 KB (pad 68)
    __shared__ float s_t[B_DIM * R_DIM];    // [b][r]   8 KB
    __shared__ int   s_qp[2][1088];         // 2 x (16 rows x 272 B) packed chunks

    const int nt = blockIdx.x;
    const int n0 = nt * 16;
    const int tid = threadIdx.x;

    // staging-role indices
    const int srow = tid >> 4;              // 0..15  (n-row within tile)
    const int scol = tid & 15;              // 0..15  (4-int32 col group)
    const int* gptr = qw + (size_t)(n0 + srow) * K_DIM + scol * 4;

    // one-time LDS stages
    for (int i = tid; i < G_DIM * 16; i += 256)
        s_ws[i] = wscales[(i >> 4) * N_DIM + n0 + (i & 15)];
    for (int i = tid; i < B_DIM * G_DIM; i += 256) {
        const int b = i >> 6, g = i & 63;
        s_as[g * 68 + b] = ascale[i];
    }
    for (int i = tid; i < B_DIM * R_DIM; i += 256) s_t[i] = t[i];

    // stage chunk 0
    {
        v4i qa[4];
        #pragma unroll
        for (int i = 0; i < 4; ++i) qa[i] = *(const v4i*)(gptr + i * 64);
        #pragma unroll
        for (int i = 0; i < 4; ++i)
            s_qp[0][srow * 68 + i * 16 + scol] = pack4(qa[i]);
    }
    __syncthreads();

    const int w = tid >> 6, lane = tid & 63;
    const int col = lane & 15, quad = lane >> 4;

    float facc[4] = {0.f, 0.f, 0.f, 0.f};
    const v4i zero = {0, 0, 0, 0};
    const v4i* xbase = xq_p + (size_t)w * G_DIM * 64 + lane;
    const char* rdbase0 = (const char*)&s_qp[0][0] + col * 272 + quad * 16;
    const char* rdbase1 = (const char*)&s_qp[1][0] + col * 272 + quad * 16;

    #pragma unroll 2
    for (int j = 0; j < 16; ++j) {
        // issue loads for chunk j+1 (consumed only in the pack below)
        v4i qa[4];
        if (j < 15) {
            const int* p = gptr + (j + 1) * 256;
            #pragma unroll
            for (int i = 0; i < 4; ++i) qa[i] = *(const v4i*)(p + i * 64);
        }
        // compute chunk j
        const char* rd = (j & 1) ? rdbase1 : rdbase0;
        #pragma unroll
        for (int gi = 0; gi < 4; ++gi) {
            const int g = j * 4 + gi;
            const v4i bq = *(const v4i*)(rd + gi * 64);
            const v4i xa = xbase[(size_t)g * 64];
            const v4i d = __builtin_amdgcn_mfma_i32_16x16x64_i8(xa, bq, zero, 0, 0, 0);
            const float wsc = s_ws[g * 16 + col];
            const float4 as4 = *(const float4*)&s_as[g * 68 + w * 16 + quad * 4];
            facc[0] = fmaf(as4.x * wsc, (float)d[0], facc[0]);
            facc[1] = fmaf(as4.y * wsc, (float)d[1], facc[1]);
            facc[2] = fmaf(as4.z * wsc, (float)d[2], facc[2]);
            facc[3] = fmaf(as4.w * wsc, (float)d[3], facc[3]);
        }
        // pack + write chunk j+1 into the other buffer (last read at j-1,
        // protected by the trailing sync of that iteration)
        if (j < 15) {
            int* wb = (j & 1) ? &s_qp[0][0] : &s_qp[1][0];
            #pragma unroll
            for (int i = 0; i < 4; ++i)
                wb[srow * 68 + i * 16 + scol] = pack4(qa[i]);
        }
        __syncthreads();
    }

    // ---- epilogue: bias + rank-32 lora, direct store ----
    const int n = n0 + col;
    float4 lu[8];
    {
        const float4* lp = (const float4*)(lora_up + (size_t)n * R_DIM);
        #pragma unroll
        for (int i = 0; i < 8; ++i) lu[i] = lp[i];
    }
    const float bs = bias[n];
    #pragma unroll
    for (int r = 0; r < 4; ++r) {
        const int b = w * 16 + quad * 4 + r;
        float acc = facc[r] + bs;
        #pragma unroll
        for (int r2 = 0; r2 < 8; ++r2) {
            const float4 tv = *(const float4*)&s_t[b * R_DIM + r2 * 4];
            acc += tv.x * lu[r2].x + tv.y * lu[r2].y +
                   tv.z * lu[r2].z + tv.w * lu[r2].w;
        }
        out[(size_t)b * N_DIM + n] = acc;
    }
}

// ---------------------------------------------------------------------------
extern "C" void kernel_launch(void* const* d_in, const int* in_sizes, int n_in,
                              void* d_out, int out_size, void* d_ws, size_t ws_size,
                              hipStream_t stream) {
    const float* x         = (const float*)d_in[0];
    const int*   q_w       = (const int*)d_in[1];
    const float* wscales   = (const float*)d_in[2];
    const float* lora_down = (const float*)d_in[3];
    const float* lora_up   = (const float*)d_in[4];
    const float* smooth    = (const float*)d_in[5];
    const float* bias      = (const float*)d_in[6];
    float* out = (float*)d_out;

    char*  xq     = (char*)d_ws;                            // 256 KB packed
    float* ascale = (float*)((char*)d_ws + 262144);         // 16 KB
    float* t      = (float*)((char*)d_ws + 262144 + 16384); // 8 KB

    hipMemsetAsync(t, 0, B_DIM * R_DIM * sizeof(float), stream);
    quant_packed_kernel<<<B_DIM * 16, 256, 0, stream>>>(x, smooth, xq, ascale);
    lora_down_kernel<<<B_DIM * 16, 256, 0, stream>>>(x, smooth, lora_down, t);
    main_fused_kernel<<<NT_DIM, 256, 0, stream>>>(q_w, wscales, (const v4i*)xq,
                                                  ascale, t, lora_up, bias, out);
}